// Round 4
// baseline (53.408 us; speedup 1.0000x reference)
//
#include <hip/hip_runtime.h>
#include <hip/hip_bf16.h>

#define ORDER 30
#define TPB 128   // threads per block == pairs per block
#define PAD 61    // LDS row stride in floats (61 coprime with 32 banks)

// Native clang vector types: __builtin_nontemporal_* requires real vector
// types, not HIP_vector_type classes.
typedef float v2f __attribute__((ext_vector_type(2)));
typedef float v4f __attribute__((ext_vector_type(4)));

// Phase 1: one thread per (b,n) pair computes T_0..T_29 for both features,
//          writes the 60 floats to its padded LDS row.
// Phase 2: block cooperatively streams LDS -> global with perfectly
//          coalesced float4 nontemporal stores (bypass L2 write-allocate:
//          the 251.7 MB output stream is never re-read).
// Output layout: out[p*60 + d*30 + n] = T_n(x[p*2 + d]).
__global__ void __launch_bounds__(TPB) cheb_encoder_kernel(
    const float* __restrict__ x, float* __restrict__ out, int npairs) {
    __shared__ float lds[TPB * PAD];
    const int tid = threadIdx.x;
    const int pair0 = blockIdx.x * TPB;
    const int p = pair0 + tid;

    if (p < npairs) {
        const v2f xv =
            __builtin_nontemporal_load(reinterpret_cast<const v2f*>(x) + p);
        float* row = &lds[tid * PAD];
#pragma unroll
        for (int d = 0; d < 2; ++d) {
            const float xx = xv[d];
            const float x2 = 2.0f * xx;
            float tm1 = 1.0f;
            float t   = xx;
            row[d * ORDER + 0] = 1.0f;
            row[d * ORDER + 1] = xx;
#pragma unroll
            for (int n = 2; n < ORDER; ++n) {
                float tn = x2 * t - tm1;
                row[d * ORDER + n] = tn;
                tm1 = t;
                t = tn;
            }
        }
    }
    __syncthreads();

    // Block output region: TPB pairs * 60 floats = TPB*15 float4 quads.
    v4f* o4 = reinterpret_cast<v4f*>(out) + (size_t)pair0 * 15;
    const int pairs_here = min(npairs - pair0, TPB);
    const int nquads = pairs_here * 15;
#pragma unroll
    for (int i = 0; i < 15; ++i) {
        const int q = i * TPB + tid;   // quad index within block region
        if (q < nquads) {
            const int pl = q / 15;               // local pair (magic-mul)
            const int k  = (q - pl * 15) * 4;    // float offset within pair
            const float* r = &lds[pl * PAD + k];
            v4f v;
            v[0] = r[0]; v[1] = r[1]; v[2] = r[2]; v[3] = r[3];
            __builtin_nontemporal_store(v, o4 + q);
        }
    }
}

extern "C" void kernel_launch(void* const* d_in, const int* in_sizes, int n_in,
                              void* d_out, int out_size, void* d_ws, size_t ws_size,
                              hipStream_t stream) {
    const float* x = (const float*)d_in[0];
    float* out = (float*)d_out;
    const int npairs = in_sizes[0] / 2;  // 16*65536 = 1,048,576 (b,n) pairs

    const int grid = (npairs + TPB - 1) / TPB;  // 8192 blocks
    cheb_encoder_kernel<<<grid, TPB, 0, stream>>>(x, out, npairs);
}

// Round 5
// 43.409 us; speedup vs baseline: 1.2303x; 1.2303x over previous
//
#include <hip/hip_runtime.h>
#include <hip/hip_bf16.h>

#define ORDER 30
#define TPB 128   // threads per block == pairs per block
#define PAD 61    // LDS row stride in floats (61 coprime with 32 banks)

// R2 configuration (best: 43.46 us, 5.98 TB/s effective = 95% of the 6.3 TB/s
// achievable ceiling). Nontemporal stores REGRESSED to 53.4 us (R4): on
// gfx950 the L2 acts as a write-combining stage for streaming stores; `nt`
// bypasses that aggregation. Keep default cache policy.
//
// Phase 1: one thread per (b,n) pair computes T_0..T_29 for both features,
//          writes the 60 floats to its padded LDS row.
// Phase 2: block cooperatively streams LDS -> global with perfectly
//          coalesced float4 stores (consecutive lanes -> consecutive 16B).
// Output layout: out[p*60 + d*30 + n] = T_n(x[p*2 + d]).
__global__ void __launch_bounds__(TPB) cheb_encoder_kernel(
    const float* __restrict__ x, float* __restrict__ out, int npairs) {
    __shared__ float lds[TPB * PAD];
    const int tid = threadIdx.x;
    const int pair0 = blockIdx.x * TPB;
    const int p = pair0 + tid;

    if (p < npairs) {
        const float2 xv = reinterpret_cast<const float2*>(x)[p];
        float* row = &lds[tid * PAD];
#pragma unroll
        for (int d = 0; d < 2; ++d) {
            const float xx = d ? xv.y : xv.x;
            const float x2 = 2.0f * xx;
            float tm1 = 1.0f;
            float t   = xx;
            row[d * ORDER + 0] = 1.0f;
            row[d * ORDER + 1] = xx;
#pragma unroll
            for (int n = 2; n < ORDER; ++n) {
                float tn = x2 * t - tm1;
                row[d * ORDER + n] = tn;
                tm1 = t;
                t = tn;
            }
        }
    }
    __syncthreads();

    // Block output region: TPB pairs * 60 floats = TPB*15 float4 quads.
    float4* o4 = reinterpret_cast<float4*>(out) + (size_t)pair0 * 15;
    const int pairs_here = min(npairs - pair0, TPB);
    const int nquads = pairs_here * 15;
#pragma unroll
    for (int i = 0; i < 15; ++i) {
        const int q = i * TPB + tid;   // quad index within block region
        if (q < nquads) {
            const int pl = q / 15;               // local pair (magic-mul)
            const int k  = (q - pl * 15) * 4;    // float offset within pair
            const float* r = &lds[pl * PAD + k];
            o4[q] = make_float4(r[0], r[1], r[2], r[3]);
        }
    }
}

extern "C" void kernel_launch(void* const* d_in, const int* in_sizes, int n_in,
                              void* d_out, int out_size, void* d_ws, size_t ws_size,
                              hipStream_t stream) {
    const float* x = (const float*)d_in[0];
    float* out = (float*)d_out;
    const int npairs = in_sizes[0] / 2;  // 16*65536 = 1,048,576 (b,n) pairs

    const int grid = (npairs + TPB - 1) / TPB;  // 8192 blocks
    cheb_encoder_kernel<<<grid, TPB, 0, stream>>>(x, out, npairs);
}